// Round 7
// baseline (112.141 us; speedup 1.0000x reference)
//
#include <hip/hip_runtime.h>
#include <hip/hip_bf16.h>

#define DD 384
#define NB 2048
#define NA 64
#define NN (NB*NA)

using bhalf8 = __attribute__((ext_vector_type(8))) __bf16;
using f32x4  = __attribute__((ext_vector_type(4))) float;
typedef unsigned short u16;
typedef unsigned char u8;

#define AS1 __attribute__((address_space(1)))
#define AS3 __attribute__((address_space(3)))

__device__ __forceinline__ void gl_lds16(const void* g, void* l) {
  __builtin_amdgcn_global_load_lds((const AS1 void*)g, (AS3 void*)l, 16, 0, 0);
}

__device__ __forceinline__ u16 f2b(float f) {
  __hip_bfloat16 h = __float2bfloat16(f);
  union { __hip_bfloat16 h; u16 u; } c; c.h = h; return c.u;
}
__device__ __forceinline__ float b2f(u16 u) {
  union { unsigned int i; float f; } c; c.i = ((unsigned int)u) << 16; return c.f;
}
__device__ __forceinline__ float celu_f(float v) {
  return v > 0.f ? v : 0.1f * (__expf(v * 10.f) - 1.f);
}
__device__ __forceinline__ bhalf8 pack8(float4 a, float4 b) {
  union { u16 us[8]; bhalf8 v; } t;
  t.us[0]=f2b(a.x); t.us[1]=f2b(a.y); t.us[2]=f2b(a.z); t.us[3]=f2b(a.w);
  t.us[4]=f2b(b.x); t.us[5]=f2b(b.y); t.us[6]=f2b(b.z); t.us[7]=f2b(b.w);
  return t.v;
}

// ---------------- prep: count + build weight images (unchanged layouts) ----------------
// B-image layout (shared by W0/W1/W2): per chunk kc (K=32): [R rows][4 slots][8 bf16],
// slot s holds k-slot j = s ^ ((r>>1)&3).
// W0img: [t][12 kc][176 r] (rows 160..175 zero; 11264 B/chunk)
// W1img: [t][ 5 kc][128 r] (8192 B/chunk)
// W2img: [t][ 4 kc][128 r] (rows 96..127 zero; 8192 B/chunk)

__global__ void k_prep(const int* __restrict__ species, int* __restrict__ counts,
                       float* __restrict__ out_sp,
                       const float* __restrict__ W0, const float* __restrict__ W1,
                       const float* __restrict__ W2, const float* __restrict__ W3,
                       u16* __restrict__ W0img, u16* __restrict__ W1img,
                       u16* __restrict__ W2img, u16* __restrict__ W3B) {
  int tid = threadIdx.x;
  int id = blockIdx.x * 256 + tid;
  if (blockIdx.x < 512) {
    __shared__ int lcnt[4];
    if (tid < 4) lcnt[tid] = 0;
    __syncthreads();
    int s = species[id];
    out_sp[id] = (float)s;
    atomicAdd(&lcnt[s], 1);
    __syncthreads();
    if (tid < 4) atomicAdd(&counts[tid], lcnt[tid]);
  }
  if (id < 270336) {
    int t = id / 67584, r1 = id % 67584;
    int kc = r1 / 5632, r2 = r1 % 5632;
    int r = r2 >> 5, rem = r2 & 31, s = rem >> 3, e = rem & 7;
    u16 v = 0;
    if (r < 160) {
      int k = kc * 32 + (s ^ ((r >> 1) & 3)) * 8 + e;
      v = f2b(W0[t * 61440 + k * 160 + r]);
    }
    W0img[id] = v;
  } else if ((id -= 270336) < 81920) {
    int t = id / 20480, r1 = id % 20480;
    int kc = r1 / 4096, r2 = r1 % 4096;
    int r = r2 >> 5, rem = r2 & 31, s = rem >> 3, e = rem & 7;
    int k = kc * 32 + (s ^ ((r >> 1) & 3)) * 8 + e;
    W1img[id] = f2b(W1[t * 20480 + k * 128 + r]);
  } else if ((id -= 81920) < 65536) {
    int t = id / 16384, r1 = id % 16384;
    int kc = r1 / 4096, r2 = r1 % 4096;
    int r = r2 >> 5, rem = r2 & 31, s = rem >> 3, e = rem & 7;
    u16 v = 0;
    if (r < 96) {
      int k = kc * 32 + (s ^ ((r >> 1) & 3)) * 8 + e;
      v = f2b(W2[t * 12288 + k * 96 + r]);
    }
    W2img[id] = v;
  } else if ((id -= 65536) < 384) {
    W3B[id] = f2b(W3[id]);
  }
}

__global__ void k_scatter(const int* __restrict__ species, const int* __restrict__ counts,
                          int* __restrict__ cursors, int* __restrict__ sorted) {
  __shared__ int lcnt[4];
  __shared__ int lbase[4];
  int tid = threadIdx.x;
  if (tid < 4) lcnt[tid] = 0;
  __syncthreads();
  int i = blockIdx.x * 256 + tid;
  int s = species[i];
  int lpos = atomicAdd(&lcnt[s], 1);
  __syncthreads();
  if (tid < 4) {
    int offs = 0;
    #pragma unroll
    for (int t = 0; t < 4; ++t) if (t < tid) offs += counts[t];
    lbase[tid] = offs + atomicAdd(&cursors[tid], lcnt[tid]);
  }
  __syncthreads();
  sorted[lbase[s] + lpos] = i;
}

// ---------------- fused MFMA MLP: M=128, 8 waves (4M x 2N), 21-phase pipeline ----------------
// LDS 65536 B -> 2 blocks/CU (16 waves/CU):
//   Bst [0,22528):      2 x 11264-B B-chunk buffers
//   Ast [22528,55296):  2 x 16384-B A-chunk buffers (fp32; L0 only)
//   sH0 [22528,65536):  u16[128][168]  (overlays Ast after L0)
//   sH1 [22528,57344):  u16[128][136]
//   sH2 [22528,49152):  u16[128][104]
// L0 B-chunk = 11 segs of 1KB: waves 0-2 stage 2 segs, waves 3-7 stage 1 ->
// per-wave L0 stage = 4 or 3 instrs -> phase-top wait is a wave-uniform branch
// vmcnt(4)/vmcnt(3). W1/W2 chunks = 8 segs -> 1 instr/wave, uniform vmcnt(1).

__global__ __launch_bounds__(512, 4) void k_mlp(
    const float* __restrict__ aev, const int* __restrict__ sorted,
    const int* __restrict__ counts,
    const u16* __restrict__ W0img, const u16* __restrict__ W1img,
    const u16* __restrict__ W2img, const u16* __restrict__ W3B,
    const float* __restrict__ b0, const float* __restrict__ b1,
    const float* __restrict__ b2, const float* __restrict__ b3,
    float* __restrict__ outE)
{
  int type = blockIdx.x, tile = blockIdx.y;
  int c0 = counts[0], c1 = counts[1], c2 = counts[2], c3 = counts[3];
  int cnt = (type == 0) ? c0 : (type == 1) ? c1 : (type == 2) ? c2 : c3;
  if (tile * 128 >= cnt) return;
  int off = 0;
  if (type > 0) off += c0;
  if (type > 1) off += c1;
  if (type > 2) off += c2;

  __shared__ uint4 smem4[4096];            // 65536 B
  u8* smem = (u8*)smem4;
  u8*  Bst = smem;                         // [2][11264]
  u8*  Ast = smem + 22528;                 // [2][16384]
  u16* sH0 = (u16*)(smem + 22528);         // [128][168]
  u16* sH1 = (u16*)(smem + 22528);         // [128][136]
  u16* sH2 = (u16*)(smem + 22528);         // [128][104]

  int tid = threadIdx.x, lane = tid & 63, w = tid >> 6;
  int wm2 = w & 3, wn2 = w >> 2, l15 = lane & 15, lk = lane >> 4;
  int base = off + tile * 128, nvalid = min(128, cnt - tile * 128);
  int wu = __builtin_amdgcn_readfirstlane(w);

  // ---- bias preload (issued before staging: older vmcnt entries, over-wait only at phase 0) ----
  float bia0[5], bia1[4], bia2[3], bia3;
  #pragma unroll
  for (int nt = 0; nt < 5; ++nt) bia0[nt] = b0[type * 160 + wn2 * 80 + nt * 16 + l15];
  #pragma unroll
  for (int nt = 0; nt < 4; ++nt) bia1[nt] = b1[type * 128 + wn2 * 64 + nt * 16 + l15];
  #pragma unroll
  for (int nt = 0; nt < 3; ++nt) bia2[nt] = b2[type * 96 + wn2 * 48 + nt * 16 + l15];
  bia3 = b3[type];

  // ---- staging sources ----
  // A: wave w stages rows [w*16, w*16+16): instr0 rows +0..7, instr1 rows +8..15;
  //    lane l -> row seg*8+(l>>3), slot l&7; global col = ((l&7)^(row&7))*4 floats.
  int arow0 = w * 16 + (lane >> 3), arow1 = arow0 + 8;
  const float* a0 = aev + (size_t)sorted[base + min(arow0, nvalid - 1)] * DD
                    + (((lane & 7) ^ (arow0 & 7)) << 2);
  const float* a1 = aev + (size_t)sorted[base + min(arow1, nvalid - 1)] * DD
                    + (((lane & 7) ^ (arow1 & 7)) << 2);
  const u8* gB0 = (const u8*)W0img + (size_t)type * 135168 + w * 1024 + lane * 16;
  const u8* gW1 = (const u8*)W1img + (size_t)type * 40960  + w * 1024 + lane * 16;
  const u8* gW2 = (const u8*)W2img + (size_t)type * 32768  + w * 1024 + lane * 16;
  u8* dA = Ast + w * 2048;                 // wave-uniform dests
  u8* dB = Bst + w * 1024;

#define STG_L0(KC, B_) do { \
    gl_lds16(a0 + (KC) * 32, dA + (B_) * 16384); \
    gl_lds16(a1 + (KC) * 32, dA + (B_) * 16384 + 1024); \
    gl_lds16(gB0 + (KC) * 11264, dB + (B_) * 11264); \
    if (wu < 3) gl_lds16(gB0 + (KC) * 11264 + 8192, dB + (B_) * 11264 + 8192); \
  } while (0)
#define STG_W(IMG, KC, B_) \
    gl_lds16((IMG) + (KC) * 8192, dB + (B_) * 11264)

  // ---- fragment offsets ----
  int aoff0 = (wm2 * 32 + l15) * 128, aoff1 = aoff0 + 2048;   // 16 rows * 128B
  int sAa = (((2 * lk)     ^ (l15 & 7)) << 4);
  int sAb = (((2 * lk + 1) ^ (l15 & 7)) << 4);
  int bsw = (lk ^ ((l15 >> 1) & 3)) << 4;

#define TOPL0() do { \
  if (wu < 3) asm volatile("s_waitcnt vmcnt(4)" ::: "memory"); \
  else        asm volatile("s_waitcnt vmcnt(3)" ::: "memory"); \
  __builtin_amdgcn_sched_barrier(0); \
  __builtin_amdgcn_s_barrier(); \
  __builtin_amdgcn_sched_barrier(0); } while (0)
#define TOPN(WN) do { \
  asm volatile("s_waitcnt vmcnt(" #WN ")" ::: "memory"); \
  __builtin_amdgcn_sched_barrier(0); \
  __builtin_amdgcn_s_barrier(); \
  __builtin_amdgcn_sched_barrier(0); } while (0)
#define TAILW() do { \
  asm volatile("s_waitcnt lgkmcnt(0)" ::: "memory"); \
  __builtin_amdgcn_sched_barrier(0); \
  __builtin_amdgcn_s_barrier(); \
  __builtin_amdgcn_sched_barrier(0); } while (0)

  // ---------- Layer 0: 12 phases ----------
  f32x4 acc0[2][5];
  #pragma unroll
  for (int mt = 0; mt < 2; ++mt)
    #pragma unroll
    for (int nt = 0; nt < 5; ++nt) acc0[mt][nt] = f32x4{0.f, 0.f, 0.f, 0.f};

  STG_L0(0, 0);
  STG_L0(1, 1);

#define PHA_BODY(KC) \
  { const u8* bA = Ast + ((KC) & 1) * 16384; \
    const u8* bB = Bst + ((KC) & 1) * 11264; \
    bhalf8 af0 = pack8(*(const float4*)(bA + aoff0 + sAa), *(const float4*)(bA + aoff0 + sAb)); \
    bhalf8 af1 = pack8(*(const float4*)(bA + aoff1 + sAa), *(const float4*)(bA + aoff1 + sAb)); \
    bhalf8 bf[5]; \
    _Pragma("unroll") \
    for (int nt = 0; nt < 5; ++nt) \
      bf[nt] = *(const bhalf8*)(bB + ((wn2 * 80 + nt * 16 + l15) << 6) + bsw); \
    _Pragma("unroll") \
    for (int nt = 0; nt < 5; ++nt) { \
      acc0[0][nt] = __builtin_amdgcn_mfma_f32_16x16x32_bf16(af0, bf[nt], acc0[0][nt], 0, 0, 0); \
      acc0[1][nt] = __builtin_amdgcn_mfma_f32_16x16x32_bf16(af1, bf[nt], acc0[1][nt], 0, 0, 0); \
    } }

#define PHA(KC, STG_) TOPL0(); PHA_BODY(KC) TAILW(); STG_;

  PHA(0, STG_L0(2, 0))  PHA(1, STG_L0(3, 1))  PHA(2, STG_L0(4, 0))
  PHA(3, STG_L0(5, 1))  PHA(4, STG_L0(6, 0))  PHA(5, STG_L0(7, 1))
  PHA(6, STG_L0(8, 0))  PHA(7, STG_L0(9, 1))  PHA(8, STG_L0(10, 0))
  PHA(9, STG_L0(11, 1)) PHA(10, STG_W(gW1, 0, 0))
  TOPN(1); PHA_BODY(11) TAILW(); STG_W(gW1, 1, 1);
#undef PHA
#undef PHA_BODY

  // L0 epilogue -> sH0 (overlays Ast; all Ast reads retired at last TAILW)
  #pragma unroll
  for (int mt = 0; mt < 2; ++mt)
    #pragma unroll
    for (int nt = 0; nt < 5; ++nt) {
      int col = wn2 * 80 + nt * 16 + l15;
      #pragma unroll
      for (int i = 0; i < 4; ++i) {
        int row = wm2 * 32 + mt * 16 + lk * 4 + i;
        sH0[row * 168 + col] = f2b(celu_f(acc0[mt][nt][i] + bia0[nt]));
      }
    }
  asm volatile("s_waitcnt lgkmcnt(0)" ::: "memory");
  __builtin_amdgcn_sched_barrier(0);

  // ---------- Layer 1: 5 phases (W1 chunks 0..4, buf = j&1) ----------
  f32x4 acc1[2][4];
  #pragma unroll
  for (int mt = 0; mt < 2; ++mt)
    #pragma unroll
    for (int nt = 0; nt < 4; ++nt) acc1[mt][nt] = f32x4{0.f, 0.f, 0.f, 0.f};

#define PHB(KC, STG_) \
  TOPN(1); \
  { const u8* bB = Bst + ((KC) & 1) * 11264; \
    bhalf8 af0 = *(const bhalf8*)&sH0[(wm2 * 32 + l15) * 168 + (KC) * 32 + lk * 8]; \
    bhalf8 af1 = *(const bhalf8*)&sH0[(wm2 * 32 + 16 + l15) * 168 + (KC) * 32 + lk * 8]; \
    bhalf8 bf[4]; \
    _Pragma("unroll") \
    for (int nt = 0; nt < 4; ++nt) \
      bf[nt] = *(const bhalf8*)(bB + ((wn2 * 64 + nt * 16 + l15) << 6) + bsw); \
    _Pragma("unroll") \
    for (int nt = 0; nt < 4; ++nt) { \
      acc1[0][nt] = __builtin_amdgcn_mfma_f32_16x16x32_bf16(af0, bf[nt], acc1[0][nt], 0, 0, 0); \
      acc1[1][nt] = __builtin_amdgcn_mfma_f32_16x16x32_bf16(af1, bf[nt], acc1[1][nt], 0, 0, 0); \
    } } \
  TAILW(); \
  STG_;

  PHB(0, STG_W(gW1, 2, 0)) PHB(1, STG_W(gW1, 3, 1)) PHB(2, STG_W(gW1, 4, 0))
  PHB(3, STG_W(gW2, 0, 1)) PHB(4, STG_W(gW2, 1, 0))
#undef PHB

  // L1 epilogue -> sH1 (overlays sH0; reads retired at last TAILW)
  #pragma unroll
  for (int mt = 0; mt < 2; ++mt)
    #pragma unroll
    for (int nt = 0; nt < 4; ++nt) {
      int col = wn2 * 64 + nt * 16 + l15;
      #pragma unroll
      for (int i = 0; i < 4; ++i) {
        int row = wm2 * 32 + mt * 16 + lk * 4 + i;
        sH1[row * 136 + col] = f2b(celu_f(acc1[mt][nt][i] + bia1[nt]));
      }
    }
  asm volatile("s_waitcnt lgkmcnt(0)" ::: "memory");
  __builtin_amdgcn_sched_barrier(0);

  // ---------- Layer 2: 4 phases (W2 chunks 0..3, buf = (j+1)&1) ----------
  f32x4 acc2[2][3];
  #pragma unroll
  for (int mt = 0; mt < 2; ++mt)
    #pragma unroll
    for (int nt = 0; nt < 3; ++nt) acc2[mt][nt] = f32x4{0.f, 0.f, 0.f, 0.f};

#define PHC(KC, WN, STG_) \
  TOPN(WN); \
  { const u8* bB = Bst + (((KC) + 1) & 1) * 11264; \
    bhalf8 af0 = *(const bhalf8*)&sH1[(wm2 * 32 + l15) * 136 + (KC) * 32 + lk * 8]; \
    bhalf8 af1 = *(const bhalf8*)&sH1[(wm2 * 32 + 16 + l15) * 136 + (KC) * 32 + lk * 8]; \
    bhalf8 bf[3]; \
    _Pragma("unroll") \
    for (int nt = 0; nt < 3; ++nt) \
      bf[nt] = *(const bhalf8*)(bB + ((wn2 * 48 + nt * 16 + l15) << 6) + bsw); \
    _Pragma("unroll") \
    for (int nt = 0; nt < 3; ++nt) { \
      acc2[0][nt] = __builtin_amdgcn_mfma_f32_16x16x32_bf16(af0, bf[nt], acc2[0][nt], 0, 0, 0); \
      acc2[1][nt] = __builtin_amdgcn_mfma_f32_16x16x32_bf16(af1, bf[nt], acc2[1][nt], 0, 0, 0); \
    } } \
  TAILW(); \
  STG_;

  PHC(0, 1, STG_W(gW2, 2, 1)) PHC(1, 1, STG_W(gW2, 3, 0)) PHC(2, 1, ) PHC(3, 0, )
#undef PHC
#undef STG_L0
#undef STG_W

  // L2 epilogue -> sH2 (overlays sH1; reads retired at last TAILW)
  #pragma unroll
  for (int mt = 0; mt < 2; ++mt)
    #pragma unroll
    for (int nt = 0; nt < 3; ++nt) {
      int col = wn2 * 48 + nt * 16 + l15;
      #pragma unroll
      for (int i = 0; i < 4; ++i) {
        int row = wm2 * 32 + mt * 16 + lk * 4 + i;
        sH2[row * 104 + col] = f2b(celu_f(acc2[mt][nt][i] + bia2[nt]));
      }
    }
  asm volatile("s_waitcnt lgkmcnt(0)" ::: "memory");
  __builtin_amdgcn_sched_barrier(0);
  __builtin_amdgcn_s_barrier();
  __builtin_amdgcn_sched_barrier(0);

  // ---------- Layer 3: [128 x 96] @ [96 x 1] + direct molecule accumulate ----------
  {
    int atom = tid >> 2;
    int q = tid & 3;
    const u16* w3 = W3B + type * 96 + q * 24;
    const u16* hrow = sH2 + atom * 104 + q * 24;
    float s = 0.f;
    #pragma unroll
    for (int i = 0; i < 3; ++i) {
      union { bhalf8 v; u16 u[8]; } hu, wu2;
      hu.v = *(const bhalf8*)&hrow[i * 8];
      wu2.v = *(const bhalf8*)&w3[i * 8];
      #pragma unroll
      for (int j = 0; j < 8; ++j)
        s += b2f(hu.u[j]) * b2f(wu2.u[j]);
    }
    s += __shfl_xor(s, 1);
    s += __shfl_xor(s, 2);
    if (q == 0 && atom < nvalid) {
      int ai = sorted[base + atom];
      atomicAdd(&outE[ai >> 6], s + bia3);
    }
  }
}

// ---------------- launch ----------------

extern "C" void kernel_launch(void* const* d_in, const int* in_sizes, int n_in,
                              void* d_out, int out_size, void* d_ws, size_t ws_size,
                              hipStream_t stream) {
  const int*   species = (const int*)d_in[0];
  const float* aev = (const float*)d_in[1];
  const float* W0 = (const float*)d_in[2];
  const float* b0 = (const float*)d_in[3];
  const float* W1 = (const float*)d_in[4];
  const float* b1 = (const float*)d_in[5];
  const float* W2 = (const float*)d_in[6];
  const float* b2 = (const float*)d_in[7];
  const float* W3 = (const float*)d_in[8];
  const float* b3 = (const float*)d_in[9];
  float* out = (float*)d_out;

  unsigned char* ws = (unsigned char*)d_ws;
  int* counts = (int*)(ws + 0);                 // [4] counts + pad + [4] cursors
  int* sorted = (int*)(ws + 64);                // int[NN]
  u16* W0img = (u16*)(ws + 1048640);            // 270336 u16
  u16* W1img = (u16*)(ws + 1589312);            // 81920 u16
  u16* W2img = (u16*)(ws + 1753152);            // 65536 u16
  u16* W3B   = (u16*)(ws + 1884224);            // 384 u16

  hipMemsetAsync(counts, 0, 48, stream);
  hipMemsetAsync(out + NN, 0, NB * 4, stream);  // zero energies (accumulated atomically)
  k_prep<<<1634, 256, 0, stream>>>(species, counts, out,
        W0, W1, W2, W3, W0img, W1img, W2img, W3B);
  k_scatter<<<NN / 256, 256, 0, stream>>>(species, counts, counts + 8, sorted);
  k_mlp<<<dim3(4, 1024), 512, 0, stream>>>(aev, sorted, counts,
        W0img, W1img, W2img, W3B, b0, b1, b2, b3, out + NN);
}

// Round 9
// 104.769 us; speedup vs baseline: 1.0704x; 1.0704x over previous
//
#include <hip/hip_runtime.h>
#include <hip/hip_bf16.h>

#define DD 384
#define NB 2048
#define NA 64
#define NN (NB*NA)

using bhalf8 = __attribute__((ext_vector_type(8))) __bf16;
using f32x4  = __attribute__((ext_vector_type(4))) float;
typedef unsigned short u16;
typedef unsigned char u8;

#define AS1 __attribute__((address_space(1)))
#define AS3 __attribute__((address_space(3)))

__device__ __forceinline__ void gl_lds16(const void* g, void* l) {
  __builtin_amdgcn_global_load_lds((const AS1 void*)g, (AS3 void*)l, 16, 0, 0);
}

__device__ __forceinline__ u16 f2b(float f) {
  __hip_bfloat16 h = __float2bfloat16(f);
  union { __hip_bfloat16 h; u16 u; } c; c.h = h; return c.u;
}
__device__ __forceinline__ float b2f(u16 u) {
  union { unsigned int i; float f; } c; c.i = ((unsigned int)u) << 16; return c.f;
}
__device__ __forceinline__ float celu_f(float v) {
  return v > 0.f ? v : 0.1f * (__expf(v * 10.f) - 1.f);
}
__device__ __forceinline__ bhalf8 pack8(float4 a, float4 b) {
  union { u16 us[8]; bhalf8 v; } t;
  t.us[0]=f2b(a.x); t.us[1]=f2b(a.y); t.us[2]=f2b(a.z); t.us[3]=f2b(a.w);
  t.us[4]=f2b(b.x); t.us[5]=f2b(b.y); t.us[6]=f2b(b.z); t.us[7]=f2b(b.w);
  return t.v;
}

// ---------------- prep: count + energy-zero + build weight images ----------------
// B-image layout (W0/W1/W2): per K=32 chunk: [R rows][4 slots][8 bf16],
// slot s holds k-slot j = s ^ ((r>>1)&3).
// W0img: [t][12 kc][160 r]  (10240 B/chunk, unpadded)
// W1img: [t][ 5 kc][128 r]  (8192 B/chunk)
// W2img: [t][ 4 kc][128 r]  (rows 96..127 zero; 8192 B/chunk)

__global__ void k_prep(const int* __restrict__ species, int* __restrict__ counts,
                       float* __restrict__ out,            // species floats + energies
                       const float* __restrict__ W0, const float* __restrict__ W1,
                       const float* __restrict__ W2, const float* __restrict__ W3,
                       u16* __restrict__ W0img, u16* __restrict__ W1img,
                       u16* __restrict__ W2img, u16* __restrict__ W3B) {
  int tid = threadIdx.x;
  int id = blockIdx.x * 256 + tid;
  if (blockIdx.x < 512) {
    __shared__ int lcnt[4];
    if (tid < 4) lcnt[tid] = 0;
    __syncthreads();
    int s = species[id];
    out[id] = (float)s;
    atomicAdd(&lcnt[s], 1);
    __syncthreads();
    if (tid < 4) atomicAdd(&counts[tid], lcnt[tid]);
  } else if (blockIdx.x < 520) {
    out[NN + (blockIdx.x - 512) * 256 + tid] = 0.f;   // zero energies (pre-k_mlp)
  }
  if (id < 245760) {
    int t = id / 61440, r1 = id % 61440;
    int kc = r1 / 5120, r2 = r1 % 5120;
    int r = r2 >> 5, rem = r2 & 31, s = rem >> 3, e = rem & 7;
    int k = kc * 32 + (s ^ ((r >> 1) & 3)) * 8 + e;
    W0img[id] = f2b(W0[t * 61440 + k * 160 + r]);
  } else if ((id -= 245760) < 81920) {
    int t = id / 20480, r1 = id % 20480;
    int kc = r1 / 4096, r2 = r1 % 4096;
    int r = r2 >> 5, rem = r2 & 31, s = rem >> 3, e = rem & 7;
    int k = kc * 32 + (s ^ ((r >> 1) & 3)) * 8 + e;
    W1img[id] = f2b(W1[t * 20480 + k * 128 + r]);
  } else if ((id -= 81920) < 65536) {
    int t = id / 16384, r1 = id % 16384;
    int kc = r1 / 4096, r2 = r1 % 4096;
    int r = r2 >> 5, rem = r2 & 31, s = rem >> 3, e = rem & 7;
    u16 v = 0;
    if (r < 96) {
      int k = kc * 32 + (s ^ ((r >> 1) & 3)) * 8 + e;
      v = f2b(W2[t * 12288 + k * 96 + r]);
    }
    W2img[id] = v;
  } else if ((id -= 65536) < 384) {
    W3B[id] = f2b(W3[id]);
  }
}

__global__ void k_scatter(const int* __restrict__ species, const int* __restrict__ counts,
                          int* __restrict__ cursors, int* __restrict__ sorted) {
  __shared__ int lcnt[4];
  __shared__ int lbase[4];
  int tid = threadIdx.x;
  if (tid < 4) lcnt[tid] = 0;
  __syncthreads();
  int i = blockIdx.x * 256 + tid;
  int s = species[i];
  int lpos = atomicAdd(&lcnt[s], 1);
  __syncthreads();
  if (tid < 4) {
    int offs = 0;
    #pragma unroll
    for (int t = 0; t < 4; ++t) if (t < tid) offs += counts[t];
    lbase[tid] = offs + atomicAdd(&cursors[tid], lcnt[tid]);
  }
  __syncthreads();
  sorted[lbase[s] + lpos] = i;
}

// ---------------- fused MFMA MLP: M=64, 4 waves (2Mx2N), 21-phase pipeline ----------------
// LDS 37888 B -> 4 blocks/CU (16 waves/CU):
//   Bst [0,20480):      2 x 10240-B L0 B-chunk buffers (10 segs: waves 0-1 stage 3, 2-3 stage 2)
//   AW  [21504,37888):  L0 A dbuf 2x8192 (fp32); later W1/W2 stream dbuf 2x8192
//   sH0 [0,21504):      u16[64][168] (over Bst, after L0)
//   sH1 [0,17408):      u16[64][136];  sH2 [0,13312): u16[64][104]
// Counted vmcnt per phase: L0 vmcnt(5)/(4) by wave, W-phases vmcnt(2).
// A-stage dest stride w*2048 (2 segs/wave of 64-row chunk); W-stage dest stride
// w*1024 (8-seg chunk, wave w owns segs {w, w+4})  <- r8 bug was using w*2048 here.

__global__ __launch_bounds__(256, 4) void k_mlp(
    const float* __restrict__ aev, const int* __restrict__ sorted,
    const int* __restrict__ counts,
    const u16* __restrict__ W0img, const u16* __restrict__ W1img,
    const u16* __restrict__ W2img, const u16* __restrict__ W3B,
    const float* __restrict__ b0, const float* __restrict__ b1,
    const float* __restrict__ b2, const float* __restrict__ b3,
    float* __restrict__ outE)
{
  int type = blockIdx.x, tile = blockIdx.y;
  int c0 = counts[0], c1 = counts[1], c2 = counts[2], c3 = counts[3];
  int cnt = (type == 0) ? c0 : (type == 1) ? c1 : (type == 2) ? c2 : c3;
  if (tile * 64 >= cnt) return;
  int off = 0;
  if (type > 0) off += c0;
  if (type > 1) off += c1;
  if (type > 2) off += c2;

  __shared__ uint4 smem4[2368];            // 37888 B
  u8* smem = (u8*)smem4;
  u8*  Bst = smem;                         // [2][10240]
  u8*  AW  = smem + 21504;                 // [2][8192]
  u16* sH0 = (u16*)smem;                   // [64][168]
  u16* sH1 = (u16*)smem;                   // [64][136]
  u16* sH2 = (u16*)smem;                   // [64][104]

  int tid = threadIdx.x, lane = tid & 63, w = tid >> 6;
  int wm = w & 1, wn = w >> 1, l15 = lane & 15, lk = lane >> 4;
  int base = off + tile * 64, nvalid = min(64, cnt - tile * 64);
  int wu = __builtin_amdgcn_readfirstlane(w);

  // ---- bias preload (oldest vmcnt entries; drained at first phase wait) ----
  float bia0[5], bia1[4], bia2[3], bia3;
  #pragma unroll
  for (int nt = 0; nt < 5; ++nt) bia0[nt] = b0[type * 160 + wn * 80 + nt * 16 + l15];
  #pragma unroll
  for (int nt = 0; nt < 4; ++nt) bia1[nt] = b1[type * 128 + wn * 64 + nt * 16 + l15];
  #pragma unroll
  for (int nt = 0; nt < 3; ++nt) bia2[nt] = b2[type * 96 + wn * 48 + nt * 16 + l15];
  bia3 = b3[type];

  // ---- staging sources ----
  int arow0 = w * 16 + (lane >> 3), arow1 = arow0 + 8;
  const float* a0 = aev + (size_t)sorted[base + min(arow0, nvalid - 1)] * DD
                    + (((lane & 7) ^ (arow0 & 7)) << 2);
  const float* a1 = aev + (size_t)sorted[base + min(arow1, nvalid - 1)] * DD
                    + (((lane & 7) ^ (arow1 & 7)) << 2);
  const u8* gB0 = (const u8*)W0img + (size_t)type * 122880 + w * 1024 + lane * 16;
  const u8* gW1 = (const u8*)W1img + (size_t)type * 40960  + w * 1024 + lane * 16;
  const u8* gW2 = (const u8*)W2img + (size_t)type * 32768  + w * 1024 + lane * 16;
  u8* dA = AW  + w * 2048;                 // A-chunk dest (2 segs/wave)
  u8* dW = AW  + w * 1024;                 // W-chunk dest (segs w, w+4)  [r8 fix]
  u8* dB = Bst + w * 1024;

#define STG_L0(KC, B_) do { \
    gl_lds16(a0 + (KC) * 32, dA + (B_) * 8192); \
    gl_lds16(a1 + (KC) * 32, dA + (B_) * 8192 + 1024); \
    gl_lds16(gB0 + (KC) * 10240,        dB + (B_) * 10240); \
    gl_lds16(gB0 + (KC) * 10240 + 4096, dB + (B_) * 10240 + 4096); \
    if (wu < 2) gl_lds16(gB0 + (KC) * 10240 + 8192, dB + (B_) * 10240 + 8192); \
  } while (0)
#define STG_W(IMG, KC, B_) do { \
    gl_lds16((IMG) + (KC) * 8192,        dW + (B_) * 8192); \
    gl_lds16((IMG) + (KC) * 8192 + 4096, dW + (B_) * 8192 + 4096); \
  } while (0)

  // ---- fragment offsets ----
  int aoff0 = (wm * 32 + l15) * 128, aoff1 = aoff0 + 2048;
  int sAa = (((2 * lk)     ^ (l15 & 7)) << 4);
  int sAb = (((2 * lk + 1) ^ (l15 & 7)) << 4);
  int bsw = (lk ^ ((l15 >> 1) & 3)) << 4;

#define TOPL0() do { \
  if (wu < 2) asm volatile("s_waitcnt vmcnt(5)" ::: "memory"); \
  else        asm volatile("s_waitcnt vmcnt(4)" ::: "memory"); \
  __builtin_amdgcn_sched_barrier(0); \
  __builtin_amdgcn_s_barrier(); \
  __builtin_amdgcn_sched_barrier(0); } while (0)
#define TOPN(WN) do { \
  asm volatile("s_waitcnt vmcnt(" #WN ")" ::: "memory"); \
  __builtin_amdgcn_sched_barrier(0); \
  __builtin_amdgcn_s_barrier(); \
  __builtin_amdgcn_sched_barrier(0); } while (0)
#define TAILW() do { \
  asm volatile("s_waitcnt lgkmcnt(0)" ::: "memory"); \
  __builtin_amdgcn_sched_barrier(0); \
  __builtin_amdgcn_s_barrier(); \
  __builtin_amdgcn_sched_barrier(0); } while (0)

  // ---------- Layer 0: 12 phases ----------
  f32x4 acc0[2][5];
  #pragma unroll
  for (int mt = 0; mt < 2; ++mt)
    #pragma unroll
    for (int nt = 0; nt < 5; ++nt) acc0[mt][nt] = f32x4{0.f, 0.f, 0.f, 0.f};

  STG_L0(0, 0);
  STG_L0(1, 1);

#define PHA_BODY(KC) \
  { const u8* bA = AW + ((KC) & 1) * 8192; \
    const u8* bB = Bst + ((KC) & 1) * 10240; \
    bhalf8 af0 = pack8(*(const float4*)(bA + aoff0 + sAa), *(const float4*)(bA + aoff0 + sAb)); \
    bhalf8 af1 = pack8(*(const float4*)(bA + aoff1 + sAa), *(const float4*)(bA + aoff1 + sAb)); \
    bhalf8 bf[5]; \
    _Pragma("unroll") \
    for (int nt = 0; nt < 5; ++nt) \
      bf[nt] = *(const bhalf8*)(bB + ((wn * 80 + nt * 16 + l15) << 6) + bsw); \
    _Pragma("unroll") \
    for (int nt = 0; nt < 5; ++nt) { \
      acc0[0][nt] = __builtin_amdgcn_mfma_f32_16x16x32_bf16(af0, bf[nt], acc0[0][nt], 0, 0, 0); \
      acc0[1][nt] = __builtin_amdgcn_mfma_f32_16x16x32_bf16(af1, bf[nt], acc0[1][nt], 0, 0, 0); \
    } }

#define PHA(KC, STG_) TOPL0(); PHA_BODY(KC) TAILW(); STG_;

  PHA(0, STG_L0(2, 0))  PHA(1, STG_L0(3, 1))  PHA(2, STG_L0(4, 0))
  PHA(3, STG_L0(5, 1))  PHA(4, STG_L0(6, 0))  PHA(5, STG_L0(7, 1))
  PHA(6, STG_L0(8, 0))  PHA(7, STG_L0(9, 1))  PHA(8, STG_L0(10, 0))
  PHA(9, STG_L0(11, 1)) PHA(10, STG_W(gW1, 0, 0))
  TOPN(2); PHA_BODY(11) TAILW(); STG_W(gW1, 1, 1);
#undef PHA
#undef PHA_BODY

  // L0 epilogue -> sH0 (over Bst; all A/B reads retired at last TAILW; W1 DMA
  // in flight targets AW region only)
  #pragma unroll
  for (int mt = 0; mt < 2; ++mt)
    #pragma unroll
    for (int nt = 0; nt < 5; ++nt) {
      int col = wn * 80 + nt * 16 + l15;
      #pragma unroll
      for (int i = 0; i < 4; ++i) {
        int row = wm * 32 + mt * 16 + lk * 4 + i;
        sH0[row * 168 + col] = f2b(celu_f(acc0[mt][nt][i] + bia0[nt]));
      }
    }
  asm volatile("s_waitcnt lgkmcnt(0)" ::: "memory");
  __builtin_amdgcn_sched_barrier(0);

  // ---------- Layer 1: 5 phases (W1 chunks 0..4 in AW, buf = kc&1) ----------
  f32x4 acc1[2][4];
  #pragma unroll
  for (int mt = 0; mt < 2; ++mt)
    #pragma unroll
    for (int nt = 0; nt < 4; ++nt) acc1[mt][nt] = f32x4{0.f, 0.f, 0.f, 0.f};

#define PHB(KC, STG_) \
  TOPN(2); \
  { const u8* bB = AW + ((KC) & 1) * 8192; \
    bhalf8 af0 = *(const bhalf8*)&sH0[(wm * 32 + l15) * 168 + (KC) * 32 + lk * 8]; \
    bhalf8 af1 = *(const bhalf8*)&sH0[(wm * 32 + 16 + l15) * 168 + (KC) * 32 + lk * 8]; \
    bhalf8 bf[4]; \
    _Pragma("unroll") \
    for (int nt = 0; nt < 4; ++nt) \
      bf[nt] = *(const bhalf8*)(bB + ((wn * 64 + nt * 16 + l15) << 6) + bsw); \
    _Pragma("unroll") \
    for (int nt = 0; nt < 4; ++nt) { \
      acc1[0][nt] = __builtin_amdgcn_mfma_f32_16x16x32_bf16(af0, bf[nt], acc1[0][nt], 0, 0, 0); \
      acc1[1][nt] = __builtin_amdgcn_mfma_f32_16x16x32_bf16(af1, bf[nt], acc1[1][nt], 0, 0, 0); \
    } } \
  TAILW(); \
  STG_;

  PHB(0, STG_W(gW1, 2, 0)) PHB(1, STG_W(gW1, 3, 1)) PHB(2, STG_W(gW1, 4, 0))
  PHB(3, STG_W(gW2, 0, 1)) PHB(4, STG_W(gW2, 1, 0))
#undef PHB

  // L1 epilogue -> sH1 (over sH0; all sH0 reads retired at last TAILW)
  #pragma unroll
  for (int mt = 0; mt < 2; ++mt)
    #pragma unroll
    for (int nt = 0; nt < 4; ++nt) {
      int col = wn * 64 + nt * 16 + l15;
      #pragma unroll
      for (int i = 0; i < 4; ++i) {
        int row = wm * 32 + mt * 16 + lk * 4 + i;
        sH1[row * 136 + col] = f2b(celu_f(acc1[mt][nt][i] + bia1[nt]));
      }
    }
  asm volatile("s_waitcnt lgkmcnt(0)" ::: "memory");
  __builtin_amdgcn_sched_barrier(0);

  // ---------- Layer 2: 4 phases (W2 chunks 0..3, buf = (kc+1)&1) ----------
  f32x4 acc2[2][3];
  #pragma unroll
  for (int mt = 0; mt < 2; ++mt)
    #pragma unroll
    for (int nt = 0; nt < 3; ++nt) acc2[mt][nt] = f32x4{0.f, 0.f, 0.f, 0.f};

#define PHC(KC, WN, STG_) \
  TOPN(WN); \
  { const u8* bB = AW + (((KC) + 1) & 1) * 8192; \
    bhalf8 af0 = *(const bhalf8*)&sH1[(wm * 32 + l15) * 136 + (KC) * 32 + lk * 8]; \
    bhalf8 af1 = *(const bhalf8*)&sH1[(wm * 32 + 16 + l15) * 136 + (KC) * 32 + lk * 8]; \
    bhalf8 bf[3]; \
    _Pragma("unroll") \
    for (int nt = 0; nt < 3; ++nt) \
      bf[nt] = *(const bhalf8*)(bB + ((wn * 48 + nt * 16 + l15) << 6) + bsw); \
    _Pragma("unroll") \
    for (int nt = 0; nt < 3; ++nt) { \
      acc2[0][nt] = __builtin_amdgcn_mfma_f32_16x16x32_bf16(af0, bf[nt], acc2[0][nt], 0, 0, 0); \
      acc2[1][nt] = __builtin_amdgcn_mfma_f32_16x16x32_bf16(af1, bf[nt], acc2[1][nt], 0, 0, 0); \
    } } \
  TAILW(); \
  STG_;

  PHC(0, 2, STG_W(gW2, 2, 1)) PHC(1, 2, STG_W(gW2, 3, 0)) PHC(2, 2, ) PHC(3, 0, )
#undef PHC
#undef STG_L0
#undef STG_W

  // L2 epilogue -> sH2 (over sH1; reads retired at last TAILW)
  #pragma unroll
  for (int mt = 0; mt < 2; ++mt)
    #pragma unroll
    for (int nt = 0; nt < 3; ++nt) {
      int col = wn * 48 + nt * 16 + l15;
      #pragma unroll
      for (int i = 0; i < 4; ++i) {
        int row = wm * 32 + mt * 16 + lk * 4 + i;
        sH2[row * 104 + col] = f2b(celu_f(acc2[mt][nt][i] + bia2[nt]));
      }
    }
  asm volatile("s_waitcnt lgkmcnt(0)" ::: "memory");
  __builtin_amdgcn_sched_barrier(0);
  __builtin_amdgcn_s_barrier();
  __builtin_amdgcn_sched_barrier(0);

  // ---------- Layer 3: [64 x 96] @ [96 x 1] + direct molecule accumulate ----------
  {
    int atom = tid >> 2;
    int q = tid & 3;
    const u16* w3 = W3B + type * 96 + q * 24;
    const u16* hrow = sH2 + atom * 104 + q * 24;
    float s = 0.f;
    #pragma unroll
    for (int i = 0; i < 3; ++i) {
      union { bhalf8 v; u16 u[8]; } hu, wu2;
      hu.v = *(const bhalf8*)&hrow[i * 8];
      wu2.v = *(const bhalf8*)&w3[i * 8];
      #pragma unroll
      for (int j = 0; j < 8; ++j)
        s += b2f(hu.u[j]) * b2f(wu2.u[j]);
    }
    s += __shfl_xor(s, 1);
    s += __shfl_xor(s, 2);
    if (q == 0 && atom < nvalid) {
      int ai = sorted[base + atom];
      atomicAdd(&outE[ai >> 6], s + bia3);
    }
  }
}

// ---------------- launch ----------------

extern "C" void kernel_launch(void* const* d_in, const int* in_sizes, int n_in,
                              void* d_out, int out_size, void* d_ws, size_t ws_size,
                              hipStream_t stream) {
  const int*   species = (const int*)d_in[0];
  const float* aev = (const float*)d_in[1];
  const float* W0 = (const float*)d_in[2];
  const float* b0 = (const float*)d_in[3];
  const float* W1 = (const float*)d_in[4];
  const float* b1 = (const float*)d_in[5];
  const float* W2 = (const float*)d_in[6];
  const float* b2 = (const float*)d_in[7];
  const float* W3 = (const float*)d_in[8];
  const float* b3 = (const float*)d_in[9];
  float* out = (float*)d_out;

  unsigned char* ws = (unsigned char*)d_ws;
  int* counts = (int*)(ws + 0);                 // [4] counts + pad + [4] cursors
  int* sorted = (int*)(ws + 64);                // int[NN]
  u16* W0img = (u16*)(ws + 1048640);            // 245760 u16
  u16* W1img = (u16*)(ws + 1540160);            // 81920 u16
  u16* W2img = (u16*)(ws + 1704000);            // 65536 u16
  u16* W3B   = (u16*)(ws + 1835072);            // 384 u16

  hipMemsetAsync(counts, 0, 48, stream);
  k_prep<<<1538, 256, 0, stream>>>(species, counts, out,
        W0, W1, W2, W3, W0img, W1img, W2img, W3B);
  k_scatter<<<NN / 256, 256, 0, stream>>>(species, counts, counts + 8, sorted);
  k_mlp<<<dim3(4, 2048), 256, 0, stream>>>(aev, sorted, counts,
        W0img, W1img, W2img, W3B, b0, b1, b2, b3, out + NN);
}

// Round 10
// 80.166 us; speedup vs baseline: 1.3989x; 1.3069x over previous
//
#include <hip/hip_runtime.h>
#include <hip/hip_bf16.h>

#define DD 384
#define NB 2048
#define NA 64
#define NN (NB*NA)

using bhalf8 = __attribute__((ext_vector_type(8))) __bf16;
using f32x4  = __attribute__((ext_vector_type(4))) float;
typedef unsigned short u16;
typedef unsigned char u8;

#define AS1 __attribute__((address_space(1)))
#define AS3 __attribute__((address_space(3)))

__device__ __forceinline__ void gl_lds16(const void* g, void* l) {
  __builtin_amdgcn_global_load_lds((const AS1 void*)g, (AS3 void*)l, 16, 0, 0);
}

__device__ __forceinline__ u16 f2b(float f) {
  __hip_bfloat16 h = __float2bfloat16(f);
  union { __hip_bfloat16 h; u16 u; } c; c.h = h; return c.u;
}
__device__ __forceinline__ float b2f(u16 u) {
  union { unsigned int i; float f; } c; c.i = ((unsigned int)u) << 16; return c.f;
}
__device__ __forceinline__ float celu_f(float v) {
  return v > 0.f ? v : 0.1f * (__expf(v * 10.f) - 1.f);
}
__device__ __forceinline__ bhalf8 pack8(float4 a, float4 b) {
  union { u16 us[8]; bhalf8 v; } t;
  t.us[0]=f2b(a.x); t.us[1]=f2b(a.y); t.us[2]=f2b(a.z); t.us[3]=f2b(a.w);
  t.us[4]=f2b(b.x); t.us[5]=f2b(b.y); t.us[6]=f2b(b.z); t.us[7]=f2b(b.w);
  return t.v;
}

// ---------------- prep: count + build weight images (layouts unchanged) ----------------
// Image (W0/W1/W2): per K=32 chunk: [R rows][4 slots][8 bf16], slot s holds
// k-slot j = s ^ ((r>>1)&3).  Rows are 64-B units -> per-(wave,nt) fragment
// loads cover a contiguous 1 KB -> fully coalesced global loads.
// W0img: [t][12 kc][160 r]  (10240 B/chunk)
// W1img: [t][ 5 kc][128 r]  (8192 B/chunk)
// W2img: [t][ 4 kc][128 r]  (rows 96..127 zero; 8192 B/chunk)

__global__ void k_prep(const int* __restrict__ species, int* __restrict__ counts,
                       float* __restrict__ out_sp,
                       const float* __restrict__ W0, const float* __restrict__ W1,
                       const float* __restrict__ W2, const float* __restrict__ W3,
                       u16* __restrict__ W0img, u16* __restrict__ W1img,
                       u16* __restrict__ W2img, u16* __restrict__ W3B) {
  int tid = threadIdx.x;
  int id = blockIdx.x * 256 + tid;
  if (blockIdx.x < 512) {
    __shared__ int lcnt[4];
    if (tid < 4) lcnt[tid] = 0;
    __syncthreads();
    int s = species[id];
    out_sp[id] = (float)s;
    atomicAdd(&lcnt[s], 1);
    __syncthreads();
    if (tid < 4) atomicAdd(&counts[tid], lcnt[tid]);
  }
  if (id < 245760) {
    int t = id / 61440, r1 = id % 61440;
    int kc = r1 / 5120, r2 = r1 % 5120;
    int r = r2 >> 5, rem = r2 & 31, s = rem >> 3, e = rem & 7;
    int k = kc * 32 + (s ^ ((r >> 1) & 3)) * 8 + e;
    W0img[id] = f2b(W0[t * 61440 + k * 160 + r]);
  } else if ((id -= 245760) < 81920) {
    int t = id / 20480, r1 = id % 20480;
    int kc = r1 / 4096, r2 = r1 % 4096;
    int r = r2 >> 5, rem = r2 & 31, s = rem >> 3, e = rem & 7;
    int k = kc * 32 + (s ^ ((r >> 1) & 3)) * 8 + e;
    W1img[id] = f2b(W1[t * 20480 + k * 128 + r]);
  } else if ((id -= 81920) < 65536) {
    int t = id / 16384, r1 = id % 16384;
    int kc = r1 / 4096, r2 = r1 % 4096;
    int r = r2 >> 5, rem = r2 & 31, s = rem >> 3, e = rem & 7;
    u16 v = 0;
    if (r < 96) {
      int k = kc * 32 + (s ^ ((r >> 1) & 3)) * 8 + e;
      v = f2b(W2[t * 12288 + k * 96 + r]);
    }
    W2img[id] = v;
  } else if ((id -= 65536) < 384) {
    W3B[id] = f2b(W3[id]);
  }
}

__global__ void k_scatter(const int* __restrict__ species, const int* __restrict__ counts,
                          int* __restrict__ cursors, int* __restrict__ sorted) {
  __shared__ int lcnt[4];
  __shared__ int lbase[4];
  int tid = threadIdx.x;
  if (tid < 4) lcnt[tid] = 0;
  __syncthreads();
  int i = blockIdx.x * 256 + tid;
  int s = species[i];
  int lpos = atomicAdd(&lcnt[s], 1);
  __syncthreads();
  if (tid < 4) {
    int offs = 0;
    #pragma unroll
    for (int t = 0; t < 4; ++t) if (t < tid) offs += counts[t];
    lbase[tid] = offs + atomicAdd(&cursors[tid], lcnt[tid]);
  }
  __syncthreads();
  sorted[lbase[s] + lpos] = i;
}

// ---------------- fused MFMA MLP: A via DMA pipeline, B via direct VGPR loads ----------------
// LDS 21504 B only:
//   Ast [0,16384): 2 x 8192-B fp32 A-chunk buffers (L0 only)
//   sH0 [0,21504) u16[64][168] (overlays Ast after L0); sH1 [0,17408); sH2 [0,13312)
// L0: 12 phases; per phase per wave: 2 A-DMA outstanding ahead -> uniform vmcnt(2);
// 5 B-fragment global loads (1 KB coalesced each, L1/L2-hit) prefetched one phase ahead.
// L1/L2: zero internal barriers (A in LDS read-only, B in registers).

__global__ __launch_bounds__(256, 5) void k_mlp(
    const float* __restrict__ aev, const int* __restrict__ sorted,
    const int* __restrict__ counts,
    const u16* __restrict__ W0img, const u16* __restrict__ W1img,
    const u16* __restrict__ W2img, const u16* __restrict__ W3B,
    const float* __restrict__ b0, const float* __restrict__ b1,
    const float* __restrict__ b2, const float* __restrict__ b3,
    float* __restrict__ atom_out)
{
  int type = blockIdx.x, tile = blockIdx.y;
  int c0 = counts[0], c1 = counts[1], c2 = counts[2], c3 = counts[3];
  int cnt = (type == 0) ? c0 : (type == 1) ? c1 : (type == 2) ? c2 : c3;
  if (tile * 64 >= cnt) return;
  int off = 0;
  if (type > 0) off += c0;
  if (type > 1) off += c1;
  if (type > 2) off += c2;

  __shared__ uint4 smem4[1344];            // 21504 B
  u8* smem = (u8*)smem4;
  u8*  Ast = smem;                         // [2][8192]
  u16* sH0 = (u16*)smem;                   // [64][168]
  u16* sH1 = (u16*)smem;                   // [64][136]
  u16* sH2 = (u16*)smem;                   // [64][104]

  int tid = threadIdx.x, lane = tid & 63, w = tid >> 6;
  int wm = w & 1, wn = w >> 1, l15 = lane & 15, lk = lane >> 4;
  int base = off + tile * 64, nvalid = min(64, cnt - tile * 64);

  // ---- A staging sources (wave w stages rows w*16..w*16+16, inverse-swizzled src) ----
  int arow0 = w * 16 + (lane >> 3), arow1 = arow0 + 8;
  const float* a0 = aev + (size_t)sorted[base + min(arow0, nvalid - 1)] * DD
                    + (((lane & 7) ^ (arow0 & 7)) << 2);
  const float* a1 = aev + (size_t)sorted[base + min(arow1, nvalid - 1)] * DD
                    + (((lane & 7) ^ (arow1 & 7)) << 2);
  u8* dA = Ast + w * 2048;

#define STG_A(KC, B_) do { \
    gl_lds16(a0 + (KC) * 32, dA + (B_) * 8192); \
    gl_lds16(a1 + (KC) * 32, dA + (B_) * 8192 + 1024); \
  } while (0)

  // ---- fragment offsets ----
  int bsw = (lk ^ ((l15 >> 1) & 3)) << 4;
  const u8* gB0 = (const u8*)W0img + (size_t)type * 122880 + ((wn * 80 + l15) << 6) + bsw;
  int aoff0 = (wm * 32 + l15) * 128, aoff1 = aoff0 + 2048;
  int sAa = (((2 * lk)     ^ (l15 & 7)) << 4);
  int sAb = (((2 * lk + 1) ^ (l15 & 7)) << 4);

#define TOPW(WN) do { \
  asm volatile("s_waitcnt vmcnt(" #WN ")" ::: "memory"); \
  __builtin_amdgcn_sched_barrier(0); \
  __builtin_amdgcn_s_barrier(); \
  __builtin_amdgcn_sched_barrier(0); } while (0)
#define TAILW() do { \
  asm volatile("s_waitcnt lgkmcnt(0)" ::: "memory"); \
  __builtin_amdgcn_sched_barrier(0); \
  __builtin_amdgcn_s_barrier(); \
  __builtin_amdgcn_sched_barrier(0); } while (0)

  // ---------- Layer 0: 12 phases, A dbuf DMA + B-in-registers ----------
  f32x4 acc0[2][5];
  #pragma unroll
  for (int mt = 0; mt < 2; ++mt)
    #pragma unroll
    for (int nt = 0; nt < 5; ++nt) acc0[mt][nt] = f32x4{0.f, 0.f, 0.f, 0.f};

  bhalf8 bf[5];
  STG_A(0, 0);
  #pragma unroll
  for (int nt = 0; nt < 5; ++nt) bf[nt] = *(const bhalf8*)(gB0 + nt * 1024);
  STG_A(1, 1);
  // ledger at each phase top: [A(kc)2, bf(kc)5, A(kc+1)2] -> vmcnt(2); last phase vmcnt(0)

#define PHA(KC, WN) \
  TOPW(WN); \
  { const u8* bA = Ast + ((KC) & 1) * 8192; \
    bhalf8 af0 = pack8(*(const float4*)(bA + aoff0 + sAa), *(const float4*)(bA + aoff0 + sAb)); \
    bhalf8 af1 = pack8(*(const float4*)(bA + aoff1 + sAa), *(const float4*)(bA + aoff1 + sAb)); \
    _Pragma("unroll") \
    for (int nt = 0; nt < 5; ++nt) { \
      acc0[0][nt] = __builtin_amdgcn_mfma_f32_16x16x32_bf16(af0, bf[nt], acc0[0][nt], 0, 0, 0); \
      acc0[1][nt] = __builtin_amdgcn_mfma_f32_16x16x32_bf16(af1, bf[nt], acc0[1][nt], 0, 0, 0); \
    } \
    if ((KC) < 11) { \
      _Pragma("unroll") \
      for (int nt = 0; nt < 5; ++nt) \
        bf[nt] = *(const bhalf8*)(gB0 + ((KC) + 1) * 10240 + nt * 1024); \
    } } \
  TAILW(); \
  if ((KC) < 10) STG_A((KC) + 2, (KC) & 1);

  PHA(0, 2)  PHA(1, 2)  PHA(2, 2)  PHA(3, 2)  PHA(4, 2)  PHA(5, 2)
  PHA(6, 2)  PHA(7, 2)  PHA(8, 2)  PHA(9, 2)  PHA(10, 2) PHA(11, 0)
#undef PHA
#undef STG_A

  // L0 epilogue -> sH0 (overlays Ast; all Ast reads/DMA retired at phase-11 top/tail)
  #pragma unroll
  for (int mt = 0; mt < 2; ++mt)
    #pragma unroll
    for (int nt = 0; nt < 5; ++nt) {
      int col = wn * 80 + nt * 16 + l15;
      float bias = b0[type * 160 + col];
      #pragma unroll
      for (int i = 0; i < 4; ++i) {
        int row = wm * 32 + mt * 16 + lk * 4 + i;
        sH0[row * 168 + col] = f2b(celu_f(acc0[mt][nt][i] + bias));
      }
    }
  TAILW();

  // ---------- Layer 1: barrier-free (A = sH0 read-only, B = registers) ----------
  const u8* gW1 = (const u8*)W1img + (size_t)type * 40960 + ((wn * 64 + l15) << 6) + bsw;
  f32x4 acc1[2][4];
  #pragma unroll
  for (int mt = 0; mt < 2; ++mt)
    #pragma unroll
    for (int nt = 0; nt < 4; ++nt) acc1[mt][nt] = f32x4{0.f, 0.f, 0.f, 0.f};

  #pragma unroll
  for (int kc = 0; kc < 5; ++kc) {
    bhalf8 af0 = *(const bhalf8*)&sH0[(wm * 32 + l15) * 168 + kc * 32 + lk * 8];
    bhalf8 af1 = *(const bhalf8*)&sH0[(wm * 32 + 16 + l15) * 168 + kc * 32 + lk * 8];
    bhalf8 bw[4];
    #pragma unroll
    for (int nt = 0; nt < 4; ++nt)
      bw[nt] = *(const bhalf8*)(gW1 + kc * 8192 + nt * 1024);
    #pragma unroll
    for (int nt = 0; nt < 4; ++nt) {
      acc1[0][nt] = __builtin_amdgcn_mfma_f32_16x16x32_bf16(af0, bw[nt], acc1[0][nt], 0, 0, 0);
      acc1[1][nt] = __builtin_amdgcn_mfma_f32_16x16x32_bf16(af1, bw[nt], acc1[1][nt], 0, 0, 0);
    }
  }
  TAILW();   // all sH0 reads done before sH1 overlay writes

  #pragma unroll
  for (int mt = 0; mt < 2; ++mt)
    #pragma unroll
    for (int nt = 0; nt < 4; ++nt) {
      int col = wn * 64 + nt * 16 + l15;
      float bias = b1[type * 128 + col];
      #pragma unroll
      for (int i = 0; i < 4; ++i) {
        int row = wm * 32 + mt * 16 + lk * 4 + i;
        sH1[row * 136 + col] = f2b(celu_f(acc1[mt][nt][i] + bias));
      }
    }
  TAILW();

  // ---------- Layer 2: barrier-free ----------
  const u8* gW2 = (const u8*)W2img + (size_t)type * 32768 + ((wn * 48 + l15) << 6) + bsw;
  f32x4 acc2[2][3];
  #pragma unroll
  for (int mt = 0; mt < 2; ++mt)
    #pragma unroll
    for (int nt = 0; nt < 3; ++nt) acc2[mt][nt] = f32x4{0.f, 0.f, 0.f, 0.f};

  #pragma unroll
  for (int kc = 0; kc < 4; ++kc) {
    bhalf8 af0 = *(const bhalf8*)&sH1[(wm * 32 + l15) * 136 + kc * 32 + lk * 8];
    bhalf8 af1 = *(const bhalf8*)&sH1[(wm * 32 + 16 + l15) * 136 + kc * 32 + lk * 8];
    bhalf8 bw[3];
    #pragma unroll
    for (int nt = 0; nt < 3; ++nt)
      bw[nt] = *(const bhalf8*)(gW2 + kc * 8192 + nt * 1024);
    #pragma unroll
    for (int nt = 0; nt < 3; ++nt) {
      acc2[0][nt] = __builtin_amdgcn_mfma_f32_16x16x32_bf16(af0, bw[nt], acc2[0][nt], 0, 0, 0);
      acc2[1][nt] = __builtin_amdgcn_mfma_f32_16x16x32_bf16(af1, bw[nt], acc2[1][nt], 0, 0, 0);
    }
  }
  TAILW();   // all sH1 reads done before sH2 overlay writes

  #pragma unroll
  for (int mt = 0; mt < 2; ++mt)
    #pragma unroll
    for (int nt = 0; nt < 3; ++nt) {
      int col = wn * 48 + nt * 16 + l15;
      float bias = b2[type * 96 + col];
      #pragma unroll
      for (int i = 0; i < 4; ++i) {
        int row = wm * 32 + mt * 16 + lk * 4 + i;
        sH2[row * 104 + col] = f2b(celu_f(acc2[mt][nt][i] + bias));
      }
    }
  TAILW();

  // ---------- Layer 3: [64 x 96] @ [96 x 1] -> atom_out ----------
  {
    int atom = tid >> 2;
    int q = tid & 3;
    const u16* w3 = W3B + type * 96 + q * 24;
    const u16* hrow = sH2 + atom * 104 + q * 24;
    float s = 0.f;
    #pragma unroll
    for (int i = 0; i < 3; ++i) {
      union { bhalf8 v; u16 u[8]; } hu, wu2;
      hu.v = *(const bhalf8*)&hrow[i * 8];
      wu2.v = *(const bhalf8*)&w3[i * 8];
      #pragma unroll
      for (int j = 0; j < 8; ++j)
        s += b2f(hu.u[j]) * b2f(wu2.u[j]);
    }
    s += __shfl_xor(s, 1);
    s += __shfl_xor(s, 2);
    if (q == 0 && atom < nvalid)
      atom_out[sorted[base + atom]] = s + b3[type];
  }
}

__global__ void k_reduce(const float* __restrict__ atom_out, float* __restrict__ out_e) {
  int mol = blockIdx.x;
  int lane = threadIdx.x;
  float v = atom_out[mol * 64 + lane];
  #pragma unroll
  for (int m = 32; m >= 1; m >>= 1) v += __shfl_xor(v, m);
  if (lane == 0) out_e[mol] = v;
}

// ---------------- launch ----------------

extern "C" void kernel_launch(void* const* d_in, const int* in_sizes, int n_in,
                              void* d_out, int out_size, void* d_ws, size_t ws_size,
                              hipStream_t stream) {
  const int*   species = (const int*)d_in[0];
  const float* aev = (const float*)d_in[1];
  const float* W0 = (const float*)d_in[2];
  const float* b0 = (const float*)d_in[3];
  const float* W1 = (const float*)d_in[4];
  const float* b1 = (const float*)d_in[5];
  const float* W2 = (const float*)d_in[6];
  const float* b2 = (const float*)d_in[7];
  const float* W3 = (const float*)d_in[8];
  const float* b3 = (const float*)d_in[9];
  float* out = (float*)d_out;

  unsigned char* ws = (unsigned char*)d_ws;
  int* counts = (int*)(ws + 0);                 // [4] counts + pad + [4] cursors
  int* sorted = (int*)(ws + 64);                // int[NN]
  float* atom_out = (float*)(ws + 524352);      // float[NN]
  u16* W0img = (u16*)(ws + 1048640);            // 245760 u16
  u16* W1img = (u16*)(ws + 1540160);            // 81920 u16
  u16* W2img = (u16*)(ws + 1704000);            // 65536 u16
  u16* W3B   = (u16*)(ws + 1835072);            // 384 u16

  hipMemsetAsync(counts, 0, 48, stream);
  k_prep<<<1538, 256, 0, stream>>>(species, counts, out,
        W0, W1, W2, W3, W0img, W1img, W2img, W3B);
  k_scatter<<<NN / 256, 256, 0, stream>>>(species, counts, counts + 8, sorted);
  k_mlp<<<dim3(4, 2048), 256, 0, stream>>>(aev, sorted, counts,
        W0img, W1img, W2img, W3B, b0, b1, b2, b3, atom_out);
  k_reduce<<<NB, 64, 0, stream>>>(atom_out, out + NN);
}

// Round 11
// 72.802 us; speedup vs baseline: 1.5404x; 1.1011x over previous
//
#include <hip/hip_runtime.h>
#include <hip/hip_bf16.h>

#define DD 384
#define NB 2048
#define NA 64
#define NN (NB*NA)

using bhalf8 = __attribute__((ext_vector_type(8))) __bf16;
using f32x4  = __attribute__((ext_vector_type(4))) float;
typedef unsigned short u16;
typedef unsigned char u8;

#define AS1 __attribute__((address_space(1)))
#define AS3 __attribute__((address_space(3)))

__device__ __forceinline__ void gl_lds16(const void* g, void* l) {
  __builtin_amdgcn_global_load_lds((const AS1 void*)g, (AS3 void*)l, 16, 0, 0);
}

__device__ __forceinline__ u16 f2b(float f) {
  __hip_bfloat16 h = __float2bfloat16(f);
  union { __hip_bfloat16 h; u16 u; } c; c.h = h; return c.u;
}
__device__ __forceinline__ float b2f(u16 u) {
  union { unsigned int i; float f; } c; c.i = ((unsigned int)u) << 16; return c.f;
}
__device__ __forceinline__ float celu_f(float v) {
  return v > 0.f ? v : 0.1f * (__expf(v * 10.f) - 1.f);
}
__device__ __forceinline__ bhalf8 pack8(float4 a, float4 b) {
  union { u16 us[8]; bhalf8 v; } t;
  t.us[0]=f2b(a.x); t.us[1]=f2b(a.y); t.us[2]=f2b(a.z); t.us[3]=f2b(a.w);
  t.us[4]=f2b(b.x); t.us[5]=f2b(b.y); t.us[6]=f2b(b.z); t.us[7]=f2b(b.w);
  return t.v;
}

// ---------------- prep: fused species-scatter + weight images ----------------
// Species blocks (0..511): write species floats to out, bin atoms by type into
// 4 disjoint regions sorted[s*NN + pos] (atomicAdd-ticketed; no prefix sum
// needed). cursors[t] ends up = count[t].
// Image (W0/W1/W2): per K=32 chunk: [R rows][4 slots][8 bf16], slot s holds
// k-slot j = s ^ ((r>>1)&3); rows are 64-B units -> 1 KB contiguous per
// (wave,nt) fragment -> coalesced global loads in k_mlp.
// W0img: [t][12 kc][160 r]; W1img: [t][5 kc][128 r]; W2img: [t][4 kc][128 r, 96+ zero]

__global__ void k_prep(const int* __restrict__ species, int* __restrict__ cursors,
                       float* __restrict__ out_sp, int* __restrict__ sorted,
                       const float* __restrict__ W0, const float* __restrict__ W1,
                       const float* __restrict__ W2, const float* __restrict__ W3,
                       u16* __restrict__ W0img, u16* __restrict__ W1img,
                       u16* __restrict__ W2img, u16* __restrict__ W3B) {
  int tid = threadIdx.x;
  int id = blockIdx.x * 256 + tid;
  if (blockIdx.x < 512) {
    __shared__ int lcnt[4];
    __shared__ int lbase[4];
    if (tid < 4) lcnt[tid] = 0;
    __syncthreads();
    int s = species[id];
    out_sp[id] = (float)s;
    int lpos = atomicAdd(&lcnt[s], 1);
    __syncthreads();
    if (tid < 4) lbase[tid] = atomicAdd(&cursors[tid], lcnt[tid]);
    __syncthreads();
    sorted[s * NN + lbase[s] + lpos] = id;
  }
  if (id < 245760) {
    int t = id / 61440, r1 = id % 61440;
    int kc = r1 / 5120, r2 = r1 % 5120;
    int r = r2 >> 5, rem = r2 & 31, s = rem >> 3, e = rem & 7;
    int k = kc * 32 + (s ^ ((r >> 1) & 3)) * 8 + e;
    W0img[id] = f2b(W0[t * 61440 + k * 160 + r]);
  } else if ((id -= 245760) < 81920) {
    int t = id / 20480, r1 = id % 20480;
    int kc = r1 / 4096, r2 = r1 % 4096;
    int r = r2 >> 5, rem = r2 & 31, s = rem >> 3, e = rem & 7;
    int k = kc * 32 + (s ^ ((r >> 1) & 3)) * 8 + e;
    W1img[id] = f2b(W1[t * 20480 + k * 128 + r]);
  } else if ((id -= 81920) < 65536) {
    int t = id / 16384, r1 = id % 16384;
    int kc = r1 / 4096, r2 = r1 % 4096;
    int r = r2 >> 5, rem = r2 & 31, s = rem >> 3, e = rem & 7;
    u16 v = 0;
    if (r < 96) {
      int k = kc * 32 + (s ^ ((r >> 1) & 3)) * 8 + e;
      v = f2b(W2[t * 12288 + k * 96 + r]);
    }
    W2img[id] = v;
  } else if ((id -= 65536) < 384) {
    W3B[id] = f2b(W3[id]);
  }
}

// ---------------- fused MFMA MLP ----------------
// LDS 24576 B:
//   Ast [0,24576): 3 x 8192-B fp32 A-chunk buffers (L0 only)
//   sH0 [0,21504) u16[64][168] (overlays Ast after L0); sH1 [0,17408); sH2 [0,13312)
// L0: 12 single-barrier phases. 3-deep A buffers: STG_A(kc+2) issued after the
// top-of-phase-kc barrier targets buf (kc-1)%3, whose phase-(kc-1) readers
// provably drained (ds_read values consumed by their own MFMAs) before that
// barrier -> no tail barrier needed. B fragments: direct global->VGPR
// (1 KB coalesced, L1/L2-hit), prefetched one phase ahead.
// vmcnt ledger at phase top: [A(kc+1):2] outstanding -> vmcnt(2); phase 11: 0.
// L1/L2: barrier-free bodies (A = LDS read-only, B = registers).

__global__ __launch_bounds__(256, 5) void k_mlp(
    const float* __restrict__ aev, const int* __restrict__ sorted,
    const int* __restrict__ counts,
    const u16* __restrict__ W0img, const u16* __restrict__ W1img,
    const u16* __restrict__ W2img, const u16* __restrict__ W3B,
    const float* __restrict__ b0, const float* __restrict__ b1,
    const float* __restrict__ b2, const float* __restrict__ b3,
    float* __restrict__ atom_out)
{
  int type = blockIdx.x, tile = blockIdx.y;
  int cnt = counts[type];
  if (tile * 64 >= cnt) return;

  __shared__ uint4 smem4[1536];            // 24576 B
  u8* smem = (u8*)smem4;
  u8*  Ast = smem;                         // [3][8192]
  u16* sH0 = (u16*)smem;                   // [64][168]
  u16* sH1 = (u16*)smem;                   // [64][136]
  u16* sH2 = (u16*)smem;                   // [64][104]

  int tid = threadIdx.x, lane = tid & 63, w = tid >> 6;
  int wm = w & 1, wn = w >> 1, l15 = lane & 15, lk = lane >> 4;
  int base = type * NN + tile * 64, nvalid = min(64, cnt - tile * 64);

  // ---- A staging sources (wave w stages rows w*16..w*16+16, inverse-swizzled src) ----
  int arow0 = w * 16 + (lane >> 3), arow1 = arow0 + 8;
  const float* a0 = aev + (size_t)sorted[base + min(arow0, nvalid - 1)] * DD
                    + (((lane & 7) ^ (arow0 & 7)) << 2);
  const float* a1 = aev + (size_t)sorted[base + min(arow1, nvalid - 1)] * DD
                    + (((lane & 7) ^ (arow1 & 7)) << 2);
  u8* dA = Ast + w * 2048;

#define STG_A(KC, B_) do { \
    gl_lds16(a0 + (KC) * 32, dA + (B_) * 8192); \
    gl_lds16(a1 + (KC) * 32, dA + (B_) * 8192 + 1024); \
  } while (0)

  // ---- fragment offsets ----
  int bsw = (lk ^ ((l15 >> 1) & 3)) << 4;
  const u8* gB0 = (const u8*)W0img + (size_t)type * 122880 + ((wn * 80 + l15) << 6) + bsw;
  int aoff0 = (wm * 32 + l15) * 128, aoff1 = aoff0 + 2048;
  int sAa = (((2 * lk)     ^ (l15 & 7)) << 4);
  int sAb = (((2 * lk + 1) ^ (l15 & 7)) << 4);

#define TOPW(WN) do { \
  asm volatile("s_waitcnt vmcnt(" #WN ")" ::: "memory"); \
  __builtin_amdgcn_sched_barrier(0); \
  __builtin_amdgcn_s_barrier(); \
  __builtin_amdgcn_sched_barrier(0); } while (0)
#define TAILW() do { \
  asm volatile("s_waitcnt lgkmcnt(0)" ::: "memory"); \
  __builtin_amdgcn_sched_barrier(0); \
  __builtin_amdgcn_s_barrier(); \
  __builtin_amdgcn_sched_barrier(0); } while (0)

  // ---------- Layer 0: 12 single-barrier phases ----------
  f32x4 acc0[2][5];
  #pragma unroll
  for (int mt = 0; mt < 2; ++mt)
    #pragma unroll
    for (int nt = 0; nt < 5; ++nt) acc0[mt][nt] = f32x4{0.f, 0.f, 0.f, 0.f};

  bhalf8 bf[5];
  STG_A(0, 0);
  #pragma unroll
  for (int nt = 0; nt < 5; ++nt) bf[nt] = *(const bhalf8*)(gB0 + nt * 1024);
  STG_A(1, 1);
  // ledger at phase-kc top: [A(kc+1):2] -> vmcnt(2); phase 11 -> vmcnt(0)

#define PHA(KC, WN) \
  TOPW(WN); \
  { const u8* bA = Ast + ((KC) % 3) * 8192; \
    bhalf8 af0 = pack8(*(const float4*)(bA + aoff0 + sAa), *(const float4*)(bA + aoff0 + sAb)); \
    bhalf8 af1 = pack8(*(const float4*)(bA + aoff1 + sAa), *(const float4*)(bA + aoff1 + sAb)); \
    _Pragma("unroll") \
    for (int nt = 0; nt < 5; ++nt) { \
      acc0[0][nt] = __builtin_amdgcn_mfma_f32_16x16x32_bf16(af0, bf[nt], acc0[0][nt], 0, 0, 0); \
      acc0[1][nt] = __builtin_amdgcn_mfma_f32_16x16x32_bf16(af1, bf[nt], acc0[1][nt], 0, 0, 0); \
    } \
    if ((KC) < 11) { \
      _Pragma("unroll") \
      for (int nt = 0; nt < 5; ++nt) \
        bf[nt] = *(const bhalf8*)(gB0 + ((KC) + 1) * 10240 + nt * 1024); \
    } } \
  if ((KC) < 10) STG_A((KC) + 2, ((KC) + 2) % 3);

  PHA(0, 2)  PHA(1, 2)  PHA(2, 2)  PHA(3, 2)  PHA(4, 2)  PHA(5, 2)
  PHA(6, 2)  PHA(7, 2)  PHA(8, 2)  PHA(9, 2)  PHA(10, 2) PHA(11, 0)
#undef PHA
#undef STG_A

  // all phase-11 reads drain naturally (consumed by MFMA); one barrier before
  // sH0 overlays the staging buffers
  TAILW();

  // L0 epilogue -> sH0
  #pragma unroll
  for (int mt = 0; mt < 2; ++mt)
    #pragma unroll
    for (int nt = 0; nt < 5; ++nt) {
      int col = wn * 80 + nt * 16 + l15;
      float bias = b0[type * 160 + col];
      #pragma unroll
      for (int i = 0; i < 4; ++i) {
        int row = wm * 32 + mt * 16 + lk * 4 + i;
        sH0[row * 168 + col] = f2b(celu_f(acc0[mt][nt][i] + bias));
      }
    }
  TAILW();

  // ---------- Layer 1: barrier-free body (A = sH0, B = registers) ----------
  const u8* gW1 = (const u8*)W1img + (size_t)type * 40960 + ((wn * 64 + l15) << 6) + bsw;
  f32x4 acc1[2][4];
  #pragma unroll
  for (int mt = 0; mt < 2; ++mt)
    #pragma unroll
    for (int nt = 0; nt < 4; ++nt) acc1[mt][nt] = f32x4{0.f, 0.f, 0.f, 0.f};

  #pragma unroll
  for (int kc = 0; kc < 5; ++kc) {
    bhalf8 af0 = *(const bhalf8*)&sH0[(wm * 32 + l15) * 168 + kc * 32 + lk * 8];
    bhalf8 af1 = *(const bhalf8*)&sH0[(wm * 32 + 16 + l15) * 168 + kc * 32 + lk * 8];
    bhalf8 bw[4];
    #pragma unroll
    for (int nt = 0; nt < 4; ++nt)
      bw[nt] = *(const bhalf8*)(gW1 + kc * 8192 + nt * 1024);
    #pragma unroll
    for (int nt = 0; nt < 4; ++nt) {
      acc1[0][nt] = __builtin_amdgcn_mfma_f32_16x16x32_bf16(af0, bw[nt], acc1[0][nt], 0, 0, 0);
      acc1[1][nt] = __builtin_amdgcn_mfma_f32_16x16x32_bf16(af1, bw[nt], acc1[1][nt], 0, 0, 0);
    }
  }
  TAILW();   // all sH0 reads done before sH1 overlay writes

  #pragma unroll
  for (int mt = 0; mt < 2; ++mt)
    #pragma unroll
    for (int nt = 0; nt < 4; ++nt) {
      int col = wn * 64 + nt * 16 + l15;
      float bias = b1[type * 128 + col];
      #pragma unroll
      for (int i = 0; i < 4; ++i) {
        int row = wm * 32 + mt * 16 + lk * 4 + i;
        sH1[row * 136 + col] = f2b(celu_f(acc1[mt][nt][i] + bias));
      }
    }
  TAILW();

  // ---------- Layer 2: barrier-free body ----------
  const u8* gW2 = (const u8*)W2img + (size_t)type * 32768 + ((wn * 48 + l15) << 6) + bsw;
  f32x4 acc2[2][3];
  #pragma unroll
  for (int mt = 0; mt < 2; ++mt)
    #pragma unroll
    for (int nt = 0; nt < 3; ++nt) acc2[mt][nt] = f32x4{0.f, 0.f, 0.f, 0.f};

  #pragma unroll
  for (int kc = 0; kc < 4; ++kc) {
    bhalf8 af0 = *(const bhalf8*)&sH1[(wm * 32 + l15) * 136 + kc * 32 + lk * 8];
    bhalf8 af1 = *(const bhalf8*)&sH1[(wm * 32 + 16 + l15) * 136 + kc * 32 + lk * 8];
    bhalf8 bw[3];
    #pragma unroll
    for (int nt = 0; nt < 3; ++nt)
      bw[nt] = *(const bhalf8*)(gW2 + kc * 8192 + nt * 1024);
    #pragma unroll
    for (int nt = 0; nt < 3; ++nt) {
      acc2[0][nt] = __builtin_amdgcn_mfma_f32_16x16x32_bf16(af0, bw[nt], acc2[0][nt], 0, 0, 0);
      acc2[1][nt] = __builtin_amdgcn_mfma_f32_16x16x32_bf16(af1, bw[nt], acc2[1][nt], 0, 0, 0);
    }
  }
  TAILW();   // all sH1 reads done before sH2 overlay writes

  #pragma unroll
  for (int mt = 0; mt < 2; ++mt)
    #pragma unroll
    for (int nt = 0; nt < 3; ++nt) {
      int col = wn * 48 + nt * 16 + l15;
      float bias = b2[type * 96 + col];
      #pragma unroll
      for (int i = 0; i < 4; ++i) {
        int row = wm * 32 + mt * 16 + lk * 4 + i;
        sH2[row * 104 + col] = f2b(celu_f(acc2[mt][nt][i] + bias));
      }
    }
  TAILW();

  // ---------- Layer 3: [64 x 96] @ [96 x 1] -> atom_out ----------
  {
    int atom = tid >> 2;
    int q = tid & 3;
    const u16* w3 = W3B + type * 96 + q * 24;
    const u16* hrow = sH2 + atom * 104 + q * 24;
    float s = 0.f;
    #pragma unroll
    for (int i = 0; i < 3; ++i) {
      union { bhalf8 v; u16 u[8]; } hu, wu2;
      hu.v = *(const bhalf8*)&hrow[i * 8];
      wu2.v = *(const bhalf8*)&w3[i * 8];
      #pragma unroll
      for (int j = 0; j < 8; ++j)
        s += b2f(hu.u[j]) * b2f(wu2.u[j]);
    }
    s += __shfl_xor(s, 1);
    s += __shfl_xor(s, 2);
    if (q == 0 && atom < nvalid)
      atom_out[sorted[base + atom]] = s + b3[type];
  }
}

__global__ void k_reduce(const float* __restrict__ atom_out, float* __restrict__ out_e) {
  int mol = blockIdx.x;
  int lane = threadIdx.x;
  float v = atom_out[mol * 64 + lane];
  #pragma unroll
  for (int m = 32; m >= 1; m >>= 1) v += __shfl_xor(v, m);
  if (lane == 0) out_e[mol] = v;
}

// ---------------- launch ----------------

extern "C" void kernel_launch(void* const* d_in, const int* in_sizes, int n_in,
                              void* d_out, int out_size, void* d_ws, size_t ws_size,
                              hipStream_t stream) {
  const int*   species = (const int*)d_in[0];
  const float* aev = (const float*)d_in[1];
  const float* W0 = (const float*)d_in[2];
  const float* b0 = (const float*)d_in[3];
  const float* W1 = (const float*)d_in[4];
  const float* b1 = (const float*)d_in[5];
  const float* W2 = (const float*)d_in[6];
  const float* b2 = (const float*)d_in[7];
  const float* W3 = (const float*)d_in[8];
  const float* b3 = (const float*)d_in[9];
  float* out = (float*)d_out;

  unsigned char* ws = (unsigned char*)d_ws;
  int* cursors = (int*)(ws + 0);                // [4] bin cursors == counts after k_prep
  int* sorted = (int*)(ws + 64);                // int[4*NN] (4 disjoint bins)
  float* atom_out = (float*)(ws + 2097216);     // float[NN]
  u16* W0img = (u16*)(ws + 2621504);            // 245760 u16
  u16* W1img = (u16*)(ws + 3113024);            // 81920 u16
  u16* W2img = (u16*)(ws + 3276864);            // 65536 u16
  u16* W3B   = (u16*)(ws + 3407936);            // 384 u16

  hipMemsetAsync(cursors, 0, 16, stream);
  k_prep<<<1538, 256, 0, stream>>>(species, cursors, out, sorted,
        W0, W1, W2, W3, W0img, W1img, W2img, W3B);
  k_mlp<<<dim3(4, 2048), 256, 0, stream>>>(aev, sorted, cursors,
        W0img, W1img, W2img, W3B, b0, b1, b2, b3, atom_out);
  k_reduce<<<NB, 64, 0, stream>>>(atom_out, out + NN);
}